// Round 13
// baseline (281.521 us; speedup 1.0000x reference)
//
#include <hip/hip_runtime.h>
#include <hip/hip_fp16.h>
#include <math.h>

#define NN 50000
#define NE 800000
#define DD 128
#define NEG_SLOPE 0.2f
#define CAP 64                    // fixed bucket capacity (max degree ~35, P(>64)~1e-17)
#define GBLK ((NN + 63) / 64)     // 782 gemm blocks (64 rows/block, 8 waves, nt split 2-way)
#define WSBLK (3 * 16384 / 256)   // 192 wsplit blocks
#define HBLK ((NE + 255) / 256)   // 3125 hist blocks
#define SBLK ((NE + 511) / 512)   // 1563 scatter blocks (512-thread)
#define AGBLK ((NN + 31) / 32)    // 1563 fused agg+gemm blocks (32 rows, 512 thr, 8 waves)

typedef short frag8 __attribute__((ext_vector_type(8)));
typedef float f32x4 __attribute__((ext_vector_type(4)));

// round-to-nearest-even fp32 -> bf16 (as ushort)
__device__ __forceinline__ unsigned bf16_rne(float x) {
  unsigned u = __float_as_uint(x);
  return (u + 0x7FFFu + ((u >> 16) & 1u)) >> 16;
}

// ---- wsplit body: W pre-split + pre-swizzle into MFMA B-fragment order ----
__device__ __forceinline__ void wsplit_body(
    int bid, const float* __restrict__ W0, const float* __restrict__ W1,
    const float* __restrict__ W2, short* __restrict__ Wh, short* __restrict__ Wl) {
  int gidx = bid * 256 + threadIdx.x;                 // 0..49151
  int L = gidx >> 14;
  int idx = gidx & 16383;
  const float* W = (L == 0) ? W0 : (L == 1) ? W1 : W2;
  int j = idx & 7;
  int lane = (idx >> 3) & 63;
  int tile = idx >> 9;                                // kt*8 + nt
  int nt = tile & 7, kt = tile >> 3;
  int k = kt * 32 + (lane >> 4) * 8 + j;
  int n = nt * 16 + (lane & 15);
  float x = W[k * DD + n];
  unsigned hu = bf16_rne(x);
  float hf = __uint_as_float(hu << 16);
  unsigned lu = bf16_rne(x - hf);
  Wh[gidx] = (short)hu;
  Wl[gidx] = (short)lu;
}

// hist + slot capture: deg count AND per-edge slot within its dst bucket (ushort).
// Atomic return -> COALESCED slot store (no dependent random write; that's the scatter pass).
__device__ __forceinline__ void hist_body(int bid, const int* __restrict__ dst,
                                          int* __restrict__ deg,
                                          unsigned short* __restrict__ edge_slot) {
  int i = bid * 256 + threadIdx.x;
  if (i < NE) edge_slot[i] = (unsigned short)atomicAdd(&deg[dst[i]], 1);
}

// fused: wsplit (192 blocks) || hist (3125 blocks)
__global__ __launch_bounds__(256) void fused_pre(
    const float* __restrict__ W0, const float* __restrict__ W1, const float* __restrict__ W2,
    short* __restrict__ Wh, short* __restrict__ Wl,
    const int* __restrict__ dst, int* __restrict__ deg,
    unsigned short* __restrict__ edge_slot) {
  if (blockIdx.x < WSBLK) wsplit_body(blockIdx.x, W0, W1, W2, Wh, Wl);
  else hist_body(blockIdx.x - WSBLK, dst, deg, edge_slot);
}

// ---- GEMM body (layer 0): z = x@W via split-bf16 MFMA. 8 waves, 64 rows/block,
// LDS-staged dbuf B (R3-proven). nt split 2-way; el/er via LDS partial reduce. ----
__device__ __forceinline__ void gemm_body(
    int bid, short (*sB)[8192], float (*elp)[64], float (*erp)[64],
    const float* __restrict__ x, const short* __restrict__ Wh, const short* __restrict__ Wl,
    const float* __restrict__ al, const float* __restrict__ ar,
    __half* __restrict__ z, float* __restrict__ el, float* __restrict__ er) {
  const int t = threadIdx.x;
  const int w = t >> 6, lane = t & 63;
  const int m = lane & 15, quad = lane >> 4;
  const int half = w >> 2, mw = w & 3;
  const int ntb = half * 4;                 // n-tile base: 0 or 4
  const int R0 = bid * 64 + mw * 16;

  auto stage = [&](int kt, int buf) {
    const uint4* gh = (const uint4*)(Wh + kt * 4096);
    const uint4* gl = (const uint4*)(Wl + kt * 4096);
    uint4* s = (uint4*)sB[buf];
    s[t] = gh[t];
    s[t + 512] = gl[t];
  };

  f32x4 acc[4];
#pragma unroll
  for (int n = 0; n < 4; n++) acc[n] = (f32x4)(0.f);

  int rA = R0 + m; if (rA > NN - 1) rA = NN - 1;  // clamp OOB rows; stores guarded

  stage(0, 0);
  __syncthreads();

#pragma unroll
  for (int kt = 0; kt < 4; kt++) {
    const int buf = kt & 1;
    if (kt < 3) stage(kt + 1, buf ^ 1);

    const float* xp = x + (size_t)rA * DD + kt * 32 + quad * 8;
    float xv[8];
    *(float4*)(xv) = *(const float4*)xp;
    *(float4*)(xv + 4) = *(const float4*)(xp + 4);
    frag8 ah, alo;
#pragma unroll
    for (int j = 0; j < 8; j++) {
      unsigned hu = bf16_rne(xv[j]);
      float hf = __uint_as_float(hu << 16);
      ah[j] = (short)hu;
      alo[j] = (short)bf16_rne(xv[j] - hf);
    }
#pragma unroll
    for (int n = 0; n < 4; n++) {
      frag8 bh = *(const frag8*)&sB[buf][(ntb + n) * 512 + lane * 8];
      frag8 bl = *(const frag8*)&sB[buf][4096 + (ntb + n) * 512 + lane * 8];
      acc[n] = __builtin_amdgcn_mfma_f32_16x16x32_bf16(alo, bh, acc[n], 0, 0, 0);
      acc[n] = __builtin_amdgcn_mfma_f32_16x16x32_bf16(ah, bl, acc[n], 0, 0, 0);
      acc[n] = __builtin_amdgcn_mfma_f32_16x16x32_bf16(ah, bh, acc[n], 0, 0, 0);
    }
    __syncthreads();
  }

  float alv[4], arv[4];
#pragma unroll
  for (int n = 0; n < 4; n++) {
    alv[n] = al[(ntb + n) * 16 + m];
    arv[n] = ar[(ntb + n) * 16 + m];
  }
#pragma unroll
  for (int r = 0; r < 4; r++) {
    float pl = 0.f, pr = 0.f;
#pragma unroll
    for (int n = 0; n < 4; n++) { pl += acc[n][r] * alv[n]; pr += acc[n][r] * arv[n]; }
#pragma unroll
    for (int off = 8; off; off >>= 1) {
      pl += __shfl_xor(pl, off, 64);
      pr += __shfl_xor(pr, off, 64);
    }
    int lrow = mw * 16 + quad * 4 + r;
    if (m == 0) { elp[half][lrow] = pl; erp[half][lrow] = pr; }
    int row = R0 + quad * 4 + r;
    if (row < NN) {
      // pack fp16 pairs: even m stores half2{col, col+1}; partner lane shares row
#pragma unroll
      for (int n = 0; n < 4; n++) {
        unsigned short hu = __half_as_ushort(__float2half(acc[n][r]));
        unsigned short hn = (unsigned short)__shfl_xor((int)hu, 1, 64);
        if ((m & 1) == 0) {
          __half2 pair = __halves2half2(__ushort_as_half(hu), __ushort_as_half(hn));
          *(__half2*)(z + (size_t)row * DD + (ntb + n) * 16 + m) = pair;
        }
      }
    }
  }
  __syncthreads();
  if (t < 64) {
    int row = bid * 64 + t;
    if (row < NN) {
      el[row] = elp[0][t] + elp[1][t];
      er[row] = erp[0][t] + erp[1][t];
    }
  }
}

// scatter into fixed-capacity buckets: csr_src[dst*CAP + slot] = src (ushort node id).
// Pure fire-and-forget random stores; slots precomputed by hist.
__device__ __forceinline__ void scatter_body(
    int bid, const int* __restrict__ src, const int* __restrict__ dst,
    const unsigned short* __restrict__ edge_slot, unsigned short* __restrict__ csr_src) {
  int i = bid * 512 + threadIdx.x;
  if (i >= NE) return;
  int slot = edge_slot[i]; if (slot > CAP - 1) slot = CAP - 1;  // theoretical overflow clamp
  csr_src[dst[i] * CAP + slot] = (unsigned short)src[i];
}

// fused: gemm0 (782 blocks first) || bucket scatter (1563 blocks)
__global__ __launch_bounds__(512) void fused_scatter_gemm(
    const float* __restrict__ x, const short* __restrict__ Wh, const short* __restrict__ Wl,
    const float* __restrict__ al, const float* __restrict__ ar,
    __half* __restrict__ z, float* __restrict__ el, float* __restrict__ er,
    const int* __restrict__ src, const int* __restrict__ dst,
    const unsigned short* __restrict__ edge_slot, unsigned short* __restrict__ csr_src) {
  __shared__ __align__(16) short sB[2][8192];
  __shared__ float elp[2][64], erp[2][64];
  if (blockIdx.x < GBLK) gemm_body(blockIdx.x, sB, elp, erp, x, Wh, Wl, al, ar, z, el, er);
  else scatter_body(blockIdx.x - GBLK, src, dst, edge_slot, csr_src);
}

// ---- per-node softmax+aggregate, 16-lane x 16B gather, 16-edge batches.
// lane = 16*g + c16: group g (0..3) handles edges jj+{g, 4+g, 8+g, 12+g} per
// iteration -> 4 x global_load_dwordx4 IN FLIGHT (2x the MLP of the 8-edge form;
// median deg~16 node completes its gather in ONE iteration). c16 covers 16B
// (4 half2) of the 256B z row. Per-lane accumulation sequence is IDENTICAL to
// the 8-edge form (g, g+4, g+8, g+12 within each 16-window) -> bit-identical.
// Cross-group shfl_xor(16/32) reduce at the end; lanes 0-15 hold the result.
// out[8]: fp32 col sums for cols c16*8..+7. ----
__device__ __forceinline__ void agg_node16(
    int node, int lane, const int* __restrict__ deg,
    const unsigned short* __restrict__ csr_src, const float* __restrict__ el,
    float erd, const __half* __restrict__ z, float* out, float* inv_s_out) {
  int dn = deg[node]; if (dn > CAP) dn = CAP;
  int beg = node * CAP;
  const int g = lane >> 4, c16 = lane & 15;
  const float4* zb = (const float4*)z;   // row = 16 float4

  int sn = 0; float wv = 0.f;
  if (lane < dn) {
    sn = csr_src[beg + lane];
    float e = el[sn] + erd;
    e = (e > 0.f) ? e : NEG_SLOPE * e;
    wv = __expf(e);
  }
  float ssum = wv;

  float acc[8];
#pragma unroll
  for (int k = 0; k < 8; k++) acc[k] = 0.f;

  for (int jj = 0; jj < dn; jj += 16) {  // padded lanes carry w=0, sn=0 -> 0 * z[0]
    float w0 = __shfl(wv, jj + g, 64);
    int   s0 = __shfl(sn, jj + g, 64);
    float w1 = __shfl(wv, jj + 4 + g, 64);
    int   s1 = __shfl(sn, jj + 4 + g, 64);
    float w2 = __shfl(wv, jj + 8 + g, 64);
    int   s2 = __shfl(sn, jj + 8 + g, 64);
    float w3 = __shfl(wv, jj + 12 + g, 64);
    int   s3 = __shfl(sn, jj + 12 + g, 64);
    float4 zv0 = zb[(size_t)s0 * 16 + c16];
    float4 zv1 = zb[(size_t)s1 * 16 + c16];
    float4 zv2 = zb[(size_t)s2 * 16 + c16];
    float4 zv3 = zb[(size_t)s3 * 16 + c16];
    const __half2* h0 = (const __half2*)&zv0;
    const __half2* h1 = (const __half2*)&zv1;
    const __half2* h2 = (const __half2*)&zv2;
    const __half2* h3 = (const __half2*)&zv3;
#pragma unroll
    for (int k = 0; k < 4; k++) {
      float2 f0 = __half22float2(h0[k]);
      float2 f1 = __half22float2(h1[k]);
      float2 f2 = __half22float2(h2[k]);
      float2 f3 = __half22float2(h3[k]);
      acc[2 * k]     += w0 * f0.x;
      acc[2 * k + 1] += w0 * f0.y;
      acc[2 * k]     += w1 * f1.x;
      acc[2 * k + 1] += w1 * f1.y;
      acc[2 * k]     += w2 * f2.x;
      acc[2 * k + 1] += w2 * f2.y;
      acc[2 * k]     += w3 * f3.x;
      acc[2 * k + 1] += w3 * f3.y;
    }
  }
#pragma unroll
  for (int k = 0; k < 8; k++) {
    acc[k] += __shfl_xor(acc[k], 16, 64);
    acc[k] += __shfl_xor(acc[k], 32, 64);
  }
#pragma unroll
  for (int off = 32; off; off >>= 1) ssum += __shfl_xor(ssum, off, 64);
  *inv_s_out = (dn > 0) ? 1.f / ssum : 0.f;
#pragma unroll
  for (int k = 0; k < 8; k++) out[k] = acc[k];
}

// ---- FUSED agg(layer L) + gemm(layer L+1): 512 thr, 8 waves, 32 nodes/block
// (R7/R10-proven geometry). Agg phase: in-block LDS work queue (flattens degree
// straggle) + 16-lane x 16B gather (agg_node16). gemm: B-fragments DIRECT from
// global (wsplit pre-swizzled, 64KB L2-hot). ----
__global__ __launch_bounds__(512) void agg_gemm(
    const int* __restrict__ deg, const unsigned short* __restrict__ csr_src,
    const float* __restrict__ el_in, const float* __restrict__ er_in,
    const __half* __restrict__ z_in, const float* __restrict__ bias,
    const short* __restrict__ Wh, const short* __restrict__ Wl,
    const float* __restrict__ al, const float* __restrict__ ar,
    __half* __restrict__ z_out, float* __restrict__ el_out, float* __restrict__ er_out) {
  // hS padded to 132 floats/row: stride%32==4 -> A-frag ds_read spreads banks
  __shared__ __align__(16) float hS[32][132];
  __shared__ float elp[4][32], erp[4][32];
  __shared__ int nq;

  const int t = threadIdx.x;
  const int w = t >> 6, lane = t & 63;
  const int R0 = blockIdx.x * 32;
  const int c16 = lane & 15;

  if (t == 0) nq = 0;
  // bias slice for this lane's 8 cols (c16*8 .. +7)
  float4 bv0 = ((const float4*)bias)[c16 * 2];
  float4 bv1 = ((const float4*)bias)[c16 * 2 + 1];
  __syncthreads();

  for (;;) {
    int lrow;
    if (lane == 0) lrow = atomicAdd(&nq, 1);
    lrow = __builtin_amdgcn_readfirstlane(lrow);
    if (lrow >= 32) break;
    int node = R0 + lrow;
    float o[8] = {0.f, 0.f, 0.f, 0.f, 0.f, 0.f, 0.f, 0.f};
    if (node < NN) {
      float inv_s, a8[8];
      agg_node16(node, lane, deg, csr_src, el_in, er_in[node], z_in, a8, &inv_s);
      o[0] = fmaxf(a8[0] * inv_s + bv0.x, 0.f);
      o[1] = fmaxf(a8[1] * inv_s + bv0.y, 0.f);
      o[2] = fmaxf(a8[2] * inv_s + bv0.z, 0.f);
      o[3] = fmaxf(a8[3] * inv_s + bv0.w, 0.f);
      o[4] = fmaxf(a8[4] * inv_s + bv1.x, 0.f);
      o[5] = fmaxf(a8[5] * inv_s + bv1.y, 0.f);
      o[6] = fmaxf(a8[6] * inv_s + bv1.z, 0.f);
      o[7] = fmaxf(a8[7] * inv_s + bv1.w, 0.f);
    }
    if (lane < 16) {
      *(float4*)&hS[lrow][c16 * 8]     = make_float4(o[0], o[1], o[2], o[3]);
      *(float4*)&hS[lrow][c16 * 8 + 4] = make_float4(o[4], o[5], o[6], o[7]);
    }
  }
  __syncthreads();

  // gemm phase: 32 rows = 2 m-tiles x 8 n-tiles; wave w -> (mt = w>>2, nt in {p, p+4})
  const int m = lane & 15, quad = lane >> 4;
  const int mt = w >> 2, p = w & 3;
  const int nt0 = p, nt1 = p + 4;
  f32x4 acc0 = (f32x4)(0.f), acc1 = (f32x4)(0.f);

#pragma unroll
  for (int kt = 0; kt < 4; kt++) {
    const float* hp = &hS[mt * 16 + m][kt * 32 + quad * 8];
    float xv[8];
    *(float4*)(xv) = *(const float4*)hp;
    *(float4*)(xv + 4) = *(const float4*)(hp + 4);
    frag8 ah, alo;
#pragma unroll
    for (int j = 0; j < 8; j++) {
      unsigned hu = bf16_rne(xv[j]);
      float hf = __uint_as_float(hu << 16);
      ah[j] = (short)hu;
      alo[j] = (short)bf16_rne(xv[j] - hf);
    }
    const short* bhp = Wh + kt * 4096 + lane * 8;
    const short* blp = Wl + kt * 4096 + lane * 8;
    frag8 bh0 = *(const frag8*)(bhp + nt0 * 512);
    frag8 bl0 = *(const frag8*)(blp + nt0 * 512);
    frag8 bh1 = *(const frag8*)(bhp + nt1 * 512);
    frag8 bl1 = *(const frag8*)(blp + nt1 * 512);
    acc0 = __builtin_amdgcn_mfma_f32_16x16x32_bf16(alo, bh0, acc0, 0, 0, 0);
    acc0 = __builtin_amdgcn_mfma_f32_16x16x32_bf16(ah, bl0, acc0, 0, 0, 0);
    acc0 = __builtin_amdgcn_mfma_f32_16x16x32_bf16(ah, bh0, acc0, 0, 0, 0);
    acc1 = __builtin_amdgcn_mfma_f32_16x16x32_bf16(alo, bh1, acc1, 0, 0, 0);
    acc1 = __builtin_amdgcn_mfma_f32_16x16x32_bf16(ah, bl1, acc1, 0, 0, 0);
    acc1 = __builtin_amdgcn_mfma_f32_16x16x32_bf16(ah, bh1, acc1, 0, 0, 0);
  }

  float alv0 = al[nt0 * 16 + m], arv0 = ar[nt0 * 16 + m];
  float alv1 = al[nt1 * 16 + m], arv1 = ar[nt1 * 16 + m];
#pragma unroll
  for (int r = 0; r < 4; r++) {
    float pl = acc0[r] * alv0 + acc1[r] * alv1;
    float pr = acc0[r] * arv0 + acc1[r] * arv1;
#pragma unroll
    for (int off = 8; off; off >>= 1) {
      pl += __shfl_xor(pl, off, 64);
      pr += __shfl_xor(pr, off, 64);
    }
    int lrow = mt * 16 + quad * 4 + r;
    if (m == 0) { elp[p][lrow] = pl; erp[p][lrow] = pr; }
    int row = R0 + lrow;
    if (row < NN) {
      unsigned short hu0 = __half_as_ushort(__float2half(acc0[r]));
      unsigned short hn0 = (unsigned short)__shfl_xor((int)hu0, 1, 64);
      unsigned short hu1 = __half_as_ushort(__float2half(acc1[r]));
      unsigned short hn1 = (unsigned short)__shfl_xor((int)hu1, 1, 64);
      if ((m & 1) == 0) {
        *(__half2*)(z_out + (size_t)row * DD + nt0 * 16 + m) =
            __halves2half2(__ushort_as_half(hu0), __ushort_as_half(hn0));
        *(__half2*)(z_out + (size_t)row * DD + nt1 * 16 + m) =
            __halves2half2(__ushort_as_half(hu1), __ushort_as_half(hn1));
      }
    }
  }
  __syncthreads();
  if (t < 32) {
    int row = R0 + t;
    if (row < NN) {
      el_out[row] = elp[0][t] + elp[1][t] + elp[2][t] + elp[3][t];
      er_out[row] = erp[0][t] + erp[1][t] + erp[2][t] + erp[3][t];
    }
  }
}

// ---- final layer: softmax + aggregation + bias + ReLU straight to output ----
__global__ __launch_bounds__(256) void gat_agg(
    const int* __restrict__ deg, const unsigned short* __restrict__ csr_src,
    const float* __restrict__ el, const float* __restrict__ er,
    const __half* __restrict__ z, const float* __restrict__ b,
    float* __restrict__ out) {
  int node = (int)((blockIdx.x * 256 + threadIdx.x) >> 6);
  int lane = threadIdx.x & 63;
  if (node >= NN) return;
  const int c16 = lane & 15;
  float inv_s, a8[8];
  agg_node16(node, lane, deg, csr_src, el, er[node], z, a8, &inv_s);
  if (lane < 16) {
    float4 bv0 = ((const float4*)b)[c16 * 2];
    float4 bv1 = ((const float4*)b)[c16 * 2 + 1];
    float4 o0, o1;
    o0.x = fmaxf(a8[0] * inv_s + bv0.x, 0.f);
    o0.y = fmaxf(a8[1] * inv_s + bv0.y, 0.f);
    o0.z = fmaxf(a8[2] * inv_s + bv0.z, 0.f);
    o0.w = fmaxf(a8[3] * inv_s + bv0.w, 0.f);
    o1.x = fmaxf(a8[4] * inv_s + bv1.x, 0.f);
    o1.y = fmaxf(a8[5] * inv_s + bv1.y, 0.f);
    o1.z = fmaxf(a8[6] * inv_s + bv1.z, 0.f);
    o1.w = fmaxf(a8[7] * inv_s + bv1.w, 0.f);
    *(float4*)(out + (size_t)node * DD + c16 * 8)     = o0;
    *(float4*)(out + (size_t)node * DD + c16 * 8 + 4) = o1;
  }
}

extern "C" void kernel_launch(void* const* d_in, const int* in_sizes, int n_in,
                              void* d_out, int out_size, void* d_ws, size_t ws_size,
                              hipStream_t stream) {
  const float* f   = (const float*)d_in[0];
  const int*   src = (const int*)d_in[1];
  const int*   dst = (const int*)d_in[2];
  const float* W[3]  = {(const float*)d_in[3], (const float*)d_in[7],  (const float*)d_in[11]};
  const float* al[3] = {(const float*)d_in[4], (const float*)d_in[8],  (const float*)d_in[12]};
  const float* ar[3] = {(const float*)d_in[5], (const float*)d_in[9],  (const float*)d_in[13]};
  const float* bb[3] = {(const float*)d_in[6], (const float*)d_in[10], (const float*)d_in[14]};

  // ws layout: Wh[3]|Wl[3] (shorts) | zA (half) | zB (half) | el|er|el2|er2 (float) |
  //            deg (int) | edge_slot (ushort) | csr_src (ushort, NN*CAP)
  short* Wh3 = (short*)d_ws;                 // 3 * 16384 shorts
  short* Wl3 = Wh3 + 3 * 16384;
  __half* zA = (__half*)(Wl3 + 3 * 16384);
  __half* zB = zA + (size_t)NN * DD;
  float* el  = (float*)(zB + (size_t)NN * DD);
  float* er  = el + NN;
  float* el2 = er + NN;
  float* er2 = el2 + NN;
  int* deg = (int*)(er2 + NN);
  unsigned short* edge_slot = (unsigned short*)(deg + NN);
  unsigned short* csr_src   = edge_slot + NE;

  hipMemsetAsync(deg, 0, NN * sizeof(int), stream);
  // wsplit || (hist + slot capture)
  fused_pre<<<WSBLK + HBLK, 256, 0, stream>>>(W[0], W[1], W[2], Wh3, Wl3, dst, deg, edge_slot);
  // gemm layer 0 || bucket scatter
  fused_scatter_gemm<<<GBLK + SBLK, 512, 0, stream>>>(f, Wh3, Wl3, al[0], ar[0],
                                                      zA, el, er,
                                                      src, dst, edge_slot, csr_src);
  // agg(L1) fused with gemm(L2): zA -> zB  (no hbuf round trip)
  agg_gemm<<<AGBLK, 512, 0, stream>>>(deg, csr_src, el, er, zA, bb[0],
                                      Wh3 + 16384, Wl3 + 16384, al[1], ar[1],
                                      zB, el2, er2);
  // agg(L2) fused with gemm(L3): zB -> zA
  agg_gemm<<<AGBLK, 512, 0, stream>>>(deg, csr_src, el2, er2, zB, bb[1],
                                      Wh3 + 2 * 16384, Wl3 + 2 * 16384, al[2], ar[2],
                                      zA, el, er);
  // final agg(L3) -> output
  gat_agg<<<(NN * 64) / 256, 256, 0, stream>>>(deg, csr_src, el, er, zA, bb[2],
                                               (float*)d_out);
}

// Round 15
// 272.649 us; speedup vs baseline: 1.0325x; 1.0325x over previous
//
#include <hip/hip_runtime.h>
#include <hip/hip_fp16.h>
#include <math.h>

#define NN 50000
#define NE 800000
#define DD 128
#define NEG_SLOPE 0.2f
#define CAP 64                    // fixed bucket capacity (max degree ~35, P(>64)~1e-17)
#define GBLK ((NN + 63) / 64)     // 782 gemm blocks (64 rows/block, 8 waves, nt split 2-way)
#define WSBLK (3 * 16384 / 256)   // 192 wsplit blocks
#define HBLK ((NE + 255) / 256)   // 3125 hist blocks
#define SBLK ((NE + 511) / 512)   // 1563 scatter blocks (512-thread)
#define AGBLK ((NN + 31) / 32)    // 1563 fused agg+gemm blocks (32 rows, 512 thr, 8 waves)

typedef short frag8 __attribute__((ext_vector_type(8)));
typedef float f32x4 __attribute__((ext_vector_type(4)));

// round-to-nearest-even fp32 -> bf16 (as ushort)
__device__ __forceinline__ unsigned bf16_rne(float x) {
  unsigned u = __float_as_uint(x);
  return (u + 0x7FFFu + ((u >> 16) & 1u)) >> 16;
}

// ---- wsplit body: W pre-split + pre-swizzle into MFMA B-fragment order ----
__device__ __forceinline__ void wsplit_body(
    int bid, const float* __restrict__ W0, const float* __restrict__ W1,
    const float* __restrict__ W2, short* __restrict__ Wh, short* __restrict__ Wl) {
  int gidx = bid * 256 + threadIdx.x;                 // 0..49151
  int L = gidx >> 14;
  int idx = gidx & 16383;
  const float* W = (L == 0) ? W0 : (L == 1) ? W1 : W2;
  int j = idx & 7;
  int lane = (idx >> 3) & 63;
  int tile = idx >> 9;                                // kt*8 + nt
  int nt = tile & 7, kt = tile >> 3;
  int k = kt * 32 + (lane >> 4) * 8 + j;
  int n = nt * 16 + (lane & 15);
  float x = W[k * DD + n];
  unsigned hu = bf16_rne(x);
  float hf = __uint_as_float(hu << 16);
  unsigned lu = bf16_rne(x - hf);
  Wh[gidx] = (short)hu;
  Wl[gidx] = (short)lu;
}

// hist + slot capture: deg count AND per-edge slot within its dst bucket (ushort).
// Atomic return -> COALESCED slot store (no dependent random write; that's the scatter pass).
__device__ __forceinline__ void hist_body(int bid, const int* __restrict__ dst,
                                          int* __restrict__ deg,
                                          unsigned short* __restrict__ edge_slot) {
  int i = bid * 256 + threadIdx.x;
  if (i < NE) edge_slot[i] = (unsigned short)atomicAdd(&deg[dst[i]], 1);
}

// fused: wsplit (192 blocks) || hist (3125 blocks)
__global__ __launch_bounds__(256) void fused_pre(
    const float* __restrict__ W0, const float* __restrict__ W1, const float* __restrict__ W2,
    short* __restrict__ Wh, short* __restrict__ Wl,
    const int* __restrict__ dst, int* __restrict__ deg,
    unsigned short* __restrict__ edge_slot) {
  if (blockIdx.x < WSBLK) wsplit_body(blockIdx.x, W0, W1, W2, Wh, Wl);
  else hist_body(blockIdx.x - WSBLK, dst, deg, edge_slot);
}

// ---- GEMM body (layer 0): z = x@W via split-bf16 MFMA. 8 waves, 64 rows/block,
// LDS-staged dbuf B (R3-proven). nt split 2-way; el/er via LDS partial reduce. ----
__device__ __forceinline__ void gemm_body(
    int bid, short (*sB)[8192], float (*elp)[64], float (*erp)[64],
    const float* __restrict__ x, const short* __restrict__ Wh, const short* __restrict__ Wl,
    const float* __restrict__ al, const float* __restrict__ ar,
    __half* __restrict__ z, float* __restrict__ el, float* __restrict__ er) {
  const int t = threadIdx.x;
  const int w = t >> 6, lane = t & 63;
  const int m = lane & 15, quad = lane >> 4;
  const int half = w >> 2, mw = w & 3;
  const int ntb = half * 4;                 // n-tile base: 0 or 4
  const int R0 = bid * 64 + mw * 16;

  auto stage = [&](int kt, int buf) {
    const uint4* gh = (const uint4*)(Wh + kt * 4096);
    const uint4* gl = (const uint4*)(Wl + kt * 4096);
    uint4* s = (uint4*)sB[buf];
    s[t] = gh[t];
    s[t + 512] = gl[t];
  };

  f32x4 acc[4];
#pragma unroll
  for (int n = 0; n < 4; n++) acc[n] = (f32x4)(0.f);

  int rA = R0 + m; if (rA > NN - 1) rA = NN - 1;  // clamp OOB rows; stores guarded

  stage(0, 0);
  __syncthreads();

#pragma unroll
  for (int kt = 0; kt < 4; kt++) {
    const int buf = kt & 1;
    if (kt < 3) stage(kt + 1, buf ^ 1);

    const float* xp = x + (size_t)rA * DD + kt * 32 + quad * 8;
    float xv[8];
    *(float4*)(xv) = *(const float4*)xp;
    *(float4*)(xv + 4) = *(const float4*)(xp + 4);
    frag8 ah, alo;
#pragma unroll
    for (int j = 0; j < 8; j++) {
      unsigned hu = bf16_rne(xv[j]);
      float hf = __uint_as_float(hu << 16);
      ah[j] = (short)hu;
      alo[j] = (short)bf16_rne(xv[j] - hf);
    }
#pragma unroll
    for (int n = 0; n < 4; n++) {
      frag8 bh = *(const frag8*)&sB[buf][(ntb + n) * 512 + lane * 8];
      frag8 bl = *(const frag8*)&sB[buf][4096 + (ntb + n) * 512 + lane * 8];
      acc[n] = __builtin_amdgcn_mfma_f32_16x16x32_bf16(alo, bh, acc[n], 0, 0, 0);
      acc[n] = __builtin_amdgcn_mfma_f32_16x16x32_bf16(ah, bl, acc[n], 0, 0, 0);
      acc[n] = __builtin_amdgcn_mfma_f32_16x16x32_bf16(ah, bh, acc[n], 0, 0, 0);
    }
    __syncthreads();
  }

  float alv[4], arv[4];
#pragma unroll
  for (int n = 0; n < 4; n++) {
    alv[n] = al[(ntb + n) * 16 + m];
    arv[n] = ar[(ntb + n) * 16 + m];
  }
#pragma unroll
  for (int r = 0; r < 4; r++) {
    float pl = 0.f, pr = 0.f;
#pragma unroll
    for (int n = 0; n < 4; n++) { pl += acc[n][r] * alv[n]; pr += acc[n][r] * arv[n]; }
#pragma unroll
    for (int off = 8; off; off >>= 1) {
      pl += __shfl_xor(pl, off, 64);
      pr += __shfl_xor(pr, off, 64);
    }
    int lrow = mw * 16 + quad * 4 + r;
    if (m == 0) { elp[half][lrow] = pl; erp[half][lrow] = pr; }
    int row = R0 + quad * 4 + r;
    if (row < NN) {
      // pack fp16 pairs: even m stores half2{col, col+1}; partner lane shares row
#pragma unroll
      for (int n = 0; n < 4; n++) {
        unsigned short hu = __half_as_ushort(__float2half(acc[n][r]));
        unsigned short hn = (unsigned short)__shfl_xor((int)hu, 1, 64);
        if ((m & 1) == 0) {
          __half2 pair = __halves2half2(__ushort_as_half(hu), __ushort_as_half(hn));
          *(__half2*)(z + (size_t)row * DD + (ntb + n) * 16 + m) = pair;
        }
      }
    }
  }
  __syncthreads();
  if (t < 64) {
    int row = bid * 64 + t;
    if (row < NN) {
      el[row] = elp[0][t] + elp[1][t];
      er[row] = erp[0][t] + erp[1][t];
    }
  }
}

// scatter into fixed-capacity buckets: csr_src[dst*CAP + slot] = src (ushort node id).
// Pure fire-and-forget random stores; slots precomputed by hist.
__device__ __forceinline__ void scatter_body(
    int bid, const int* __restrict__ src, const int* __restrict__ dst,
    const unsigned short* __restrict__ edge_slot, unsigned short* __restrict__ csr_src) {
  int i = bid * 512 + threadIdx.x;
  if (i >= NE) return;
  int slot = edge_slot[i]; if (slot > CAP - 1) slot = CAP - 1;  // theoretical overflow clamp
  csr_src[dst[i] * CAP + slot] = (unsigned short)src[i];
}

// fused: gemm0 (782 blocks first) || bucket scatter (1563 blocks)
__global__ __launch_bounds__(512) void fused_scatter_gemm(
    const float* __restrict__ x, const short* __restrict__ Wh, const short* __restrict__ Wl,
    const float* __restrict__ al, const float* __restrict__ ar,
    __half* __restrict__ z, float* __restrict__ el, float* __restrict__ er,
    const int* __restrict__ src, const int* __restrict__ dst,
    const unsigned short* __restrict__ edge_slot, unsigned short* __restrict__ csr_src) {
  __shared__ __align__(16) short sB[2][8192];
  __shared__ float elp[2][64], erp[2][64];
  if (blockIdx.x < GBLK) gemm_body(blockIdx.x, sB, elp, erp, x, Wh, Wl, al, ar, z, el, er);
  else scatter_body(blockIdx.x - GBLK, src, dst, edge_slot, csr_src);
}

// ---- per-node softmax+aggregate, 16-lane x 16B gather form (R12-proven optimum).
// lane = 16*g + c16: group g (0..3) handles edges jj+{g, 4+g} per iteration
// (8 edges/iter, 2 x global_load_dwordx4 in flight); c16 covers 16B (4 half2)
// of the 256B z row. R13's 4-load/16-edge widening REGRESSED (occupancy 56->45%,
// +5us): the agg phase is L2-miss-bandwidth bound, not MLP-bound — keep batches
// shallow. Cross-group shfl_xor(16/32) reduce at the end; lanes 0-15 hold result.
// out[8]: fp32 col sums for cols c16*8..+7. ----
__device__ __forceinline__ void agg_node16(
    int node, int lane, const int* __restrict__ deg,
    const unsigned short* __restrict__ csr_src, const float* __restrict__ el,
    float erd, const __half* __restrict__ z, float* out, float* inv_s_out) {
  int dn = deg[node]; if (dn > CAP) dn = CAP;
  int beg = node * CAP;
  const int g = lane >> 4, c16 = lane & 15;
  const float4* zb = (const float4*)z;   // row = 16 float4

  int sn = 0; float wv = 0.f;
  if (lane < dn) {
    sn = csr_src[beg + lane];
    float e = el[sn] + erd;
    e = (e > 0.f) ? e : NEG_SLOPE * e;
    wv = __expf(e);
  }
  float ssum = wv;

  float acc[8];
#pragma unroll
  for (int k = 0; k < 8; k++) acc[k] = 0.f;

  for (int jj = 0; jj < dn; jj += 8) {   // padded lanes carry w=0, sn=0 -> 0 * z[0]
    float w0 = __shfl(wv, jj + g, 64);
    int   s0 = __shfl(sn, jj + g, 64);
    float w1 = __shfl(wv, jj + 4 + g, 64);
    int   s1 = __shfl(sn, jj + 4 + g, 64);
    float4 zv0 = zb[(size_t)s0 * 16 + c16];
    float4 zv1 = zb[(size_t)s1 * 16 + c16];
    const __half2* h0 = (const __half2*)&zv0;
    const __half2* h1 = (const __half2*)&zv1;
#pragma unroll
    for (int k = 0; k < 4; k++) {
      float2 f0 = __half22float2(h0[k]);
      float2 f1 = __half22float2(h1[k]);
      acc[2 * k]     += w0 * f0.x;
      acc[2 * k + 1] += w0 * f0.y;
      acc[2 * k]     += w1 * f1.x;
      acc[2 * k + 1] += w1 * f1.y;
    }
  }
#pragma unroll
  for (int k = 0; k < 8; k++) {
    acc[k] += __shfl_xor(acc[k], 16, 64);
    acc[k] += __shfl_xor(acc[k], 32, 64);
  }
#pragma unroll
  for (int off = 32; off; off >>= 1) ssum += __shfl_xor(ssum, off, 64);
  *inv_s_out = (dn > 0) ? 1.f / ssum : 0.f;
#pragma unroll
  for (int k = 0; k < 8; k++) out[k] = acc[k];
}

// ---- FUSED agg(layer L) + gemm(layer L+1): 512 thr, 8 waves, 32 nodes/block
// (R7/R10-proven geometry). Agg phase: in-block LDS work queue (flattens degree
// straggle) + 16-lane x 16B gather (agg_node16). gemm: B-fragments DIRECT from
// global (wsplit pre-swizzled, 64KB L2-hot). ----
__global__ __launch_bounds__(512) void agg_gemm(
    const int* __restrict__ deg, const unsigned short* __restrict__ csr_src,
    const float* __restrict__ el_in, const float* __restrict__ er_in,
    const __half* __restrict__ z_in, const float* __restrict__ bias,
    const short* __restrict__ Wh, const short* __restrict__ Wl,
    const float* __restrict__ al, const float* __restrict__ ar,
    __half* __restrict__ z_out, float* __restrict__ el_out, float* __restrict__ er_out) {
  // hS padded to 132 floats/row: stride%32==4 -> A-frag ds_read spreads banks
  __shared__ __align__(16) float hS[32][132];
  __shared__ float elp[4][32], erp[4][32];
  __shared__ int nq;

  const int t = threadIdx.x;
  const int w = t >> 6, lane = t & 63;
  const int R0 = blockIdx.x * 32;
  const int c16 = lane & 15;

  if (t == 0) nq = 0;
  // bias slice for this lane's 8 cols (c16*8 .. +7)
  float4 bv0 = ((const float4*)bias)[c16 * 2];
  float4 bv1 = ((const float4*)bias)[c16 * 2 + 1];
  __syncthreads();

  for (;;) {
    int lrow;
    if (lane == 0) lrow = atomicAdd(&nq, 1);
    lrow = __builtin_amdgcn_readfirstlane(lrow);
    if (lrow >= 32) break;
    int node = R0 + lrow;
    float o[8] = {0.f, 0.f, 0.f, 0.f, 0.f, 0.f, 0.f, 0.f};
    if (node < NN) {
      float inv_s, a8[8];
      agg_node16(node, lane, deg, csr_src, el_in, er_in[node], z_in, a8, &inv_s);
      o[0] = fmaxf(a8[0] * inv_s + bv0.x, 0.f);
      o[1] = fmaxf(a8[1] * inv_s + bv0.y, 0.f);
      o[2] = fmaxf(a8[2] * inv_s + bv0.z, 0.f);
      o[3] = fmaxf(a8[3] * inv_s + bv0.w, 0.f);
      o[4] = fmaxf(a8[4] * inv_s + bv1.x, 0.f);
      o[5] = fmaxf(a8[5] * inv_s + bv1.y, 0.f);
      o[6] = fmaxf(a8[6] * inv_s + bv1.z, 0.f);
      o[7] = fmaxf(a8[7] * inv_s + bv1.w, 0.f);
    }
    if (lane < 16) {
      *(float4*)&hS[lrow][c16 * 8]     = make_float4(o[0], o[1], o[2], o[3]);
      *(float4*)&hS[lrow][c16 * 8 + 4] = make_float4(o[4], o[5], o[6], o[7]);
    }
  }
  __syncthreads();

  // gemm phase: 32 rows = 2 m-tiles x 8 n-tiles; wave w -> (mt = w>>2, nt in {p, p+4})
  const int m = lane & 15, quad = lane >> 4;
  const int mt = w >> 2, p = w & 3;
  const int nt0 = p, nt1 = p + 4;
  f32x4 acc0 = (f32x4)(0.f), acc1 = (f32x4)(0.f);

#pragma unroll
  for (int kt = 0; kt < 4; kt++) {
    const float* hp = &hS[mt * 16 + m][kt * 32 + quad * 8];
    float xv[8];
    *(float4*)(xv) = *(const float4*)hp;
    *(float4*)(xv + 4) = *(const float4*)(hp + 4);
    frag8 ah, alo;
#pragma unroll
    for (int j = 0; j < 8; j++) {
      unsigned hu = bf16_rne(xv[j]);
      float hf = __uint_as_float(hu << 16);
      ah[j] = (short)hu;
      alo[j] = (short)bf16_rne(xv[j] - hf);
    }
    const short* bhp = Wh + kt * 4096 + lane * 8;
    const short* blp = Wl + kt * 4096 + lane * 8;
    frag8 bh0 = *(const frag8*)(bhp + nt0 * 512);
    frag8 bl0 = *(const frag8*)(blp + nt0 * 512);
    frag8 bh1 = *(const frag8*)(bhp + nt1 * 512);
    frag8 bl1 = *(const frag8*)(blp + nt1 * 512);
    acc0 = __builtin_amdgcn_mfma_f32_16x16x32_bf16(alo, bh0, acc0, 0, 0, 0);
    acc0 = __builtin_amdgcn_mfma_f32_16x16x32_bf16(ah, bl0, acc0, 0, 0, 0);
    acc0 = __builtin_amdgcn_mfma_f32_16x16x32_bf16(ah, bh0, acc0, 0, 0, 0);
    acc1 = __builtin_amdgcn_mfma_f32_16x16x32_bf16(alo, bh1, acc1, 0, 0, 0);
    acc1 = __builtin_amdgcn_mfma_f32_16x16x32_bf16(ah, bl1, acc1, 0, 0, 0);
    acc1 = __builtin_amdgcn_mfma_f32_16x16x32_bf16(ah, bh1, acc1, 0, 0, 0);
  }

  float alv0 = al[nt0 * 16 + m], arv0 = ar[nt0 * 16 + m];
  float alv1 = al[nt1 * 16 + m], arv1 = ar[nt1 * 16 + m];
#pragma unroll
  for (int r = 0; r < 4; r++) {
    float pl = acc0[r] * alv0 + acc1[r] * alv1;
    float pr = acc0[r] * arv0 + acc1[r] * arv1;
#pragma unroll
    for (int off = 8; off; off >>= 1) {
      pl += __shfl_xor(pl, off, 64);
      pr += __shfl_xor(pr, off, 64);
    }
    int lrow = mt * 16 + quad * 4 + r;
    if (m == 0) { elp[p][lrow] = pl; erp[p][lrow] = pr; }
    int row = R0 + lrow;
    if (row < NN) {
      unsigned short hu0 = __half_as_ushort(__float2half(acc0[r]));
      unsigned short hn0 = (unsigned short)__shfl_xor((int)hu0, 1, 64);
      unsigned short hu1 = __half_as_ushort(__float2half(acc1[r]));
      unsigned short hn1 = (unsigned short)__shfl_xor((int)hu1, 1, 64);
      if ((m & 1) == 0) {
        *(__half2*)(z_out + (size_t)row * DD + nt0 * 16 + m) =
            __halves2half2(__ushort_as_half(hu0), __ushort_as_half(hn0));
        *(__half2*)(z_out + (size_t)row * DD + nt1 * 16 + m) =
            __halves2half2(__ushort_as_half(hu1), __ushort_as_half(hn1));
      }
    }
  }
  __syncthreads();
  if (t < 32) {
    int row = R0 + t;
    if (row < NN) {
      el_out[row] = elp[0][t] + elp[1][t] + elp[2][t] + elp[3][t];
      er_out[row] = erp[0][t] + erp[1][t] + erp[2][t] + erp[3][t];
    }
  }
}

// ---- final layer: softmax + aggregation + bias + ReLU straight to output ----
__global__ __launch_bounds__(256) void gat_agg(
    const int* __restrict__ deg, const unsigned short* __restrict__ csr_src,
    const float* __restrict__ el, const float* __restrict__ er,
    const __half* __restrict__ z, const float* __restrict__ b,
    float* __restrict__ out) {
  int node = (int)((blockIdx.x * 256 + threadIdx.x) >> 6);
  int lane = threadIdx.x & 63;
  if (node >= NN) return;
  const int c16 = lane & 15;
  float inv_s, a8[8];
  agg_node16(node, lane, deg, csr_src, el, er[node], z, a8, &inv_s);
  if (lane < 16) {
    float4 bv0 = ((const float4*)b)[c16 * 2];
    float4 bv1 = ((const float4*)b)[c16 * 2 + 1];
    float4 o0, o1;
    o0.x = fmaxf(a8[0] * inv_s + bv0.x, 0.f);
    o0.y = fmaxf(a8[1] * inv_s + bv0.y, 0.f);
    o0.z = fmaxf(a8[2] * inv_s + bv0.z, 0.f);
    o0.w = fmaxf(a8[3] * inv_s + bv0.w, 0.f);
    o1.x = fmaxf(a8[4] * inv_s + bv1.x, 0.f);
    o1.y = fmaxf(a8[5] * inv_s + bv1.y, 0.f);
    o1.z = fmaxf(a8[6] * inv_s + bv1.z, 0.f);
    o1.w = fmaxf(a8[7] * inv_s + bv1.w, 0.f);
    *(float4*)(out + (size_t)node * DD + c16 * 8)     = o0;
    *(float4*)(out + (size_t)node * DD + c16 * 8 + 4) = o1;
  }
}

extern "C" void kernel_launch(void* const* d_in, const int* in_sizes, int n_in,
                              void* d_out, int out_size, void* d_ws, size_t ws_size,
                              hipStream_t stream) {
  const float* f   = (const float*)d_in[0];
  const int*   src = (const int*)d_in[1];
  const int*   dst = (const int*)d_in[2];
  const float* W[3]  = {(const float*)d_in[3], (const float*)d_in[7],  (const float*)d_in[11]};
  const float* al[3] = {(const float*)d_in[4], (const float*)d_in[8],  (const float*)d_in[12]};
  const float* ar[3] = {(const float*)d_in[5], (const float*)d_in[9],  (const float*)d_in[13]};
  const float* bb[3] = {(const float*)d_in[6], (const float*)d_in[10], (const float*)d_in[14]};

  // ws layout: Wh[3]|Wl[3] (shorts) | zA (half) | zB (half) | el|er|el2|er2 (float) |
  //            deg (int) | edge_slot (ushort) | csr_src (ushort, NN*CAP)
  short* Wh3 = (short*)d_ws;                 // 3 * 16384 shorts
  short* Wl3 = Wh3 + 3 * 16384;
  __half* zA = (__half*)(Wl3 + 3 * 16384);
  __half* zB = zA + (size_t)NN * DD;
  float* el  = (float*)(zB + (size_t)NN * DD);
  float* er  = el + NN;
  float* el2 = er + NN;
  float* er2 = el2 + NN;
  int* deg = (int*)(er2 + NN);
  unsigned short* edge_slot = (unsigned short*)(deg + NN);
  unsigned short* csr_src   = edge_slot + NE;

  hipMemsetAsync(deg, 0, NN * sizeof(int), stream);
  // wsplit || (hist + slot capture)
  fused_pre<<<WSBLK + HBLK, 256, 0, stream>>>(W[0], W[1], W[2], Wh3, Wl3, dst, deg, edge_slot);
  // gemm layer 0 || bucket scatter
  fused_scatter_gemm<<<GBLK + SBLK, 512, 0, stream>>>(f, Wh3, Wl3, al[0], ar[0],
                                                      zA, el, er,
                                                      src, dst, edge_slot, csr_src);
  // agg(L1) fused with gemm(L2): zA -> zB  (no hbuf round trip)
  agg_gemm<<<AGBLK, 512, 0, stream>>>(deg, csr_src, el, er, zA, bb[0],
                                      Wh3 + 16384, Wl3 + 16384, al[1], ar[1],
                                      zB, el2, er2);
  // agg(L2) fused with gemm(L3): zB -> zA
  agg_gemm<<<AGBLK, 512, 0, stream>>>(deg, csr_src, el2, er2, zB, bb[1],
                                      Wh3 + 2 * 16384, Wl3 + 2 * 16384, al[2], ar[2],
                                      zA, el, er);
  // final agg(L3) -> output
  gat_agg<<<(NN * 64) / 256, 256, 0, stream>>>(deg, csr_src, el, er, zA, bb[2],
                                               (float*)d_out);
}